// Round 6
// baseline (1174.524 us; speedup 1.0000x reference)
//
#include <hip/hip_runtime.h>

// GoL CNN v7: occupancy attack. Evidence: v4/v5/v6 all ~50us with LDS 31%,
// MFMA 29%, VALU 11% busy, 1 block/CU, occupancy 19% -> latency-bound.
//  - grid 512 (one output row per block), 8-wave K-split, acc0 only.
//  - LDS 32 KB: ring-4 rowbuf (24 KB) UNIONED with Red[8][1024] f32 (32 KB);
//    disjoint lifetimes (final GOLBAR/syncthreads separates them).
//  - __launch_bounds__(512,4): 128-VGPR cap -> 2 blocks/CU co-resident,
//    4 waves/SIMD of mutually-unsynchronized work to hide L2/LDS latency.
//  - single A/F register sets (no SW pipeline - compiler overrode it anyway).
//  - XCD-chunked bijective swizzle: 64 contiguous rows (2 batches) per XCD.

typedef _Float16 f16;
typedef _Float16 f16x8 __attribute__((ext_vector_type(8)));
typedef float f32x4 __attribute__((ext_vector_type(4)));
typedef float f32x16 __attribute__((ext_vector_type(16)));

// iterated wrap-pad index map, j in [0,94): middle j-31; borders alternate.
__device__ __forceinline__ int mwrap(int j) {
  int t = j - 31;
  if ((unsigned)t <= 31u) return t;          // middle
  if (t < 0) return (j & 1) ? 0 : 31;        // left border
  return (j & 1) ? 0 : 31;                   // right border
}

// hpad layout: [16b][32ch][32y][96x] f16 (x' in [0,94) valid)
// Wf frag-major: per layer, chunk=(c*32+ky)*2+kxh, then [lane(64)][8 f16]
//   lane: co=lane&31, s=lane>>5; elements w[co][c][ky][kxh*16+s*8+j]

// Gather the 8 B-fragments of channel cc (ring slot cc&3) into FD[4][2].
#define LOADF(FD, cc)                                                       \
  {                                                                         \
    const int so_ = ((cc) & 3) * 6144;                                      \
    _Pragma("unroll")                                                       \
    for (int j_ = 0; j_ < 4; ++j_) {                                        \
      const int* Rj_ = (const int*)(lds0 + V[j_] + so_);                    \
      int4 t0_, t1_;                                                        \
      t0_.x = Rj_[0]; t0_.y = Rj_[1]; t0_.z = Rj_[2]; t0_.w = Rj_[3];       \
      t1_.x = Rj_[8]; t1_.y = Rj_[9]; t1_.z = Rj_[10]; t1_.w = Rj_[11];     \
      FD[j_][0] = __builtin_bit_cast(f16x8, t0_);                           \
      FD[j_][1] = __builtin_bit_cast(f16x8, t1_);                           \
    }                                                                       \
  }

// 8 MFMAs consuming register-resident fragments.
#define MFMAC(AUSE, FD)                                                     \
  {                                                                         \
    _Pragma("unroll")                                                       \
    for (int kyi_ = 0; kyi_ < 4; ++kyi_) {                                  \
      _Pragma("unroll")                                                     \
      for (int kxh_ = 0; kxh_ < 2; ++kxh_) {                                \
        acc0 = __builtin_amdgcn_mfma_f32_32x32x16_f16(                      \
            AUSE[kyi_ * 2 + kxh_], FD[kyi_][kxh_], acc0, 0, 0, 0);          \
      }                                                                     \
    }                                                                       \
  }

// Producer barrier: drain LDS ops only; VMEM stays in flight (rule #18 fence).
#define GOLBAR()                                       \
  asm volatile("s_waitcnt lgkmcnt(0)" ::: "memory");   \
  __builtin_amdgcn_sched_barrier(0);                   \
  __builtin_amdgcn_s_barrier();

template <int CIN, bool RELU, bool PRE>
__global__ __launch_bounds__(512, 4) void gemm3(
    const void* __restrict__ Wv,       // PRE: f16 frag-major; else fp32 raw
    const f16* __restrict__ hp_in,     // [16][CIN][32][96]
    const float* __restrict__ bias,    // [32]
    f16* __restrict__ hp_out) {        // [16][32][32][96]
  // union: rowbuf ring-4 [4][32][96] f16 (24 KB) | Red [8][1024] f32 (32 KB)
  __shared__ __align__(16) char smem[32768];
  char* lds0 = smem;
  float* Red = (float*)smem;

  const int tid = threadIdx.x;
  const int lane = tid & 63;
  const int w = tid >> 6;        // wave 0..7: owns ky in {4w..4w+3}
  const int ox = lane & 31;      // B n-index / A m-index (co)
  const int s = lane >> 5;       // k-half within mfma

  // XCD-chunked bijective swizzle (512 % 8 == 0): XCD k gets 64 contiguous
  // row-ids = 2 full batches -> L2 locality for staged activations.
  const int bid = blockIdx.x;
  const int pair0 = ((bid & 7) << 6) | (bid >> 3);
  const int b = pair0 >> 5;
  const int oy = pair0 & 31;     // single output row per block

  // row staging decode: 384 units of f16x8 cover 32 rows x 96 (waves 0-5)
  const int rrow = tid / 12, rseg = tid - rrow * 12;  // valid if tid<384

  // rows needed by this wave: y = mwrap(2*oy + 4w + j), j = 0..3
  const int bi = ox + 4 * s;
  int V[4];
#pragma unroll
  for (int j = 0; j < 4; ++j)
    V[j] = mwrap(2 * oy + 4 * w + j) * 192 + bi * 4;  // byte offset in slot

  const int wroff = rrow * 192 + rseg * 16;  // staging write byte offset

  f32x16 acc0 = {};
  f16x8 A[8];
  f16x8 F[4][2];
  f16x8 stgA = {}, stgB = {};

  auto loadA = [&](int c, f16x8* dst) {
#pragma unroll
    for (int kyi = 0; kyi < 4; ++kyi) {
#pragma unroll
      for (int kxh = 0; kxh < 2; ++kxh) {
        const int ky = 4 * w + kyi;
        const int chunk = (c * 32 + ky) * 2 + kxh;
        if constexpr (PRE) {
          const f16* Wl = (const f16*)Wv;
          dst[kyi * 2 + kxh] = *(const f16x8*)(Wl + (size_t)chunk * 512 + lane * 8);
        } else {
          const float* Wl = (const float*)Wv;
          const float* sp = Wl + (((size_t)(ox * CIN + c) * 32 + ky) * 32 + kxh * 16 + s * 8);
          f32x4 u0 = *(const f32x4*)sp;
          f32x4 u1 = *(const f32x4*)(sp + 4);
          f16x8 v;
          v[0] = (f16)u0[0]; v[1] = (f16)u0[1]; v[2] = (f16)u0[2]; v[3] = (f16)u0[3];
          v[4] = (f16)u1[0]; v[5] = (f16)u1[1]; v[6] = (f16)u1[2]; v[7] = (f16)u1[3];
          dst[kyi * 2 + kxh] = v;
        }
      }
    }
  };
  auto loadRowTo = [&](int c, f16x8& dst) {
    if (tid < 384)
      dst = *(const f16x8*)(hp_in + ((size_t)(b * CIN + c) * 32 + rrow) * 96 + rseg * 8);
  };
  auto writeSlot = [&](int slot, const f16x8& src) {
    if (tid < 384) *(f16x8*)(lds0 + slot * 6144 + wroff) = src;
  };

  if constexpr (CIN == 1) {
    loadRowTo(0, stgA);
    writeSlot(0, stgA);
    loadA(0, A);
    __syncthreads();
    LOADF(F, 0);
    MFMAC(A, F);
  } else {
    static_assert(CIN % 2 == 0, "CIN must be 1 or even");
    loadRowTo(0, stgA); loadRowTo(1, stgB);
    writeSlot(0, stgA); writeSlot(1, stgB);
    __syncthreads();

#pragma unroll 1
    for (int c0 = 0; c0 < CIN; c0 += 2) {
      const bool more = (c0 + 2 < CIN);
      if (more) {  // stage next 2 channels; lands during this group's compute
        loadRowTo(c0 + 2, stgA);
        loadRowTo(c0 + 3, stgB);
      }
      loadA(c0, A);
      LOADF(F, c0);
      MFMAC(A, F);
      loadA(c0 + 1, A);
      LOADF(F, c0 + 1);
      MFMAC(A, F);
      if (more) {  // ring-4 group-2: writes (c0+2,c0+3)&3 disjoint from reads
        writeSlot((c0 + 2) & 3, stgA);
        writeSlot((c0 + 3) & 3, stgB);
      }
      GOLBAR();
    }
  }

  // rowbuf is dead; Red overlays the same LDS. Barrier so every wave's
  // rowbuf reads are drained before Red writes (needed for CIN==1 path).
  __syncthreads();

  // 8-way K reduction: every wave dumps its 16 partials, all threads reduce
#pragma unroll
  for (int r = 0; r < 16; ++r) Red[w * 1024 + r * 64 + lane] = acc0[r];
  __syncthreads();

#pragma unroll
  for (int k2 = 0; k2 < 2; ++k2) {
    const int o = tid + 512 * k2;          // 1024 outputs: [co][ox]
    const int co = (o >> 5) & 31, oxx = o & 31;
    const int idx = ((co & 3) + 4 * (co >> 3)) * 64 + ((co >> 2) & 1) * 32 + oxx;
    float v = bias[co];
#pragma unroll
    for (int w8 = 0; w8 < 8; ++w8) v += Red[w8 * 1024 + idx];
    if (RELU) v = fmaxf(v, 0.f);
    const f16 hv = (f16)v;
    f16* base = hp_out + ((size_t)(b * 32 + co) * 32 + oy) * 96;
    base[oxx + 31] = hv;
    if (oxx == 0) {
#pragma unroll
      for (int j = 1; j <= 29; j += 2) base[j] = hv;
#pragma unroll
      for (int j = 63; j <= 93; j += 2) base[j] = hv;
    }
    if (oxx == 31) {
#pragma unroll
      for (int j = 0; j <= 30; j += 2) base[j] = hv;
#pragma unroll
      for (int j = 64; j <= 92; j += 2) base[j] = hv;
    }
  }
}

// x (fp32 [16][1][32][32]) -> xpad f16 [16][1][32][96]
__global__ void pad_x_kernel(const float* __restrict__ x, f16* __restrict__ xp) {
  const int i = blockIdx.x * 256 + threadIdx.x;  // 16*32*94 = 48128
  if (i >= 48128) return;
  const int bq = i / 3008, r = i - bq * 3008;
  const int y = r / 94, j = r - y * 94;
  xp[bq * 3072 + y * 96 + j] = (f16)x[(bq * 32 + y) * 32 + mwrap(j)];
}

// build frag-major f16 weights: in_w (64 chunks) + 20 hidden layers (2048 each)
__global__ void convert_w3(const float* __restrict__ in_w,
                           const float* __restrict__ convs_w,
                           f16* __restrict__ WfIn, f16* __restrict__ WfH) {
  const int total = 4096 + 20 * 131072;  // units of (chunk,lane)
  for (int g = blockIdx.x * blockDim.x + threadIdx.x; g < total;
       g += gridDim.x * blockDim.x) {
    const float* src;
    f16* dst;
    int chunk, lanE, c, ky, kxh;
    if (g < 4096) {
      chunk = g >> 6; lanE = g & 63;
      kxh = chunk & 1; ky = chunk >> 1; c = 0;
      const int co = lanE & 31, ss = lanE >> 5;
      src = in_w + ((size_t)(co * 1 + 0) * 32 + ky) * 32 + kxh * 16 + ss * 8;
      dst = WfIn + (size_t)chunk * 512 + lanE * 8;
    } else {
      const int h = g - 4096;
      const int layer = h >> 17, r = h & 131071;
      chunk = r >> 6; lanE = r & 63;
      kxh = chunk & 1;
      const int t = chunk >> 1;
      ky = t & 31; c = t >> 5;
      const int co = lanE & 31, ss = lanE >> 5;
      src = convs_w + (size_t)layer * 1048576 +
            ((size_t)(co * 32 + c) * 32 + ky) * 32 + kxh * 16 + ss * 8;
      dst = WfH + (size_t)layer * 1048576 + (size_t)chunk * 512 + lanE * 8;
    }
    f32x4 u0 = *(const f32x4*)src;
    f32x4 u1 = *(const f32x4*)(src + 4);
    f16x8 v;
    v[0] = (f16)u0[0]; v[1] = (f16)u0[1]; v[2] = (f16)u0[2]; v[3] = (f16)u0[3];
    v[4] = (f16)u1[0]; v[5] = (f16)u1[1]; v[6] = (f16)u1[2]; v[7] = (f16)u1[3];
    *(f16x8*)dst = v;
  }
}

// 1x1 out conv from hpad final: out[b][0][oy][ox] fp32
__global__ void out_conv3(const f16* __restrict__ hp,
                          const float* __restrict__ ow,
                          const float* __restrict__ ob,
                          float* __restrict__ out) {
  const int o = blockIdx.x * 256 + threadIdx.x;  // 16384
  const int b = o >> 10, oy = (o >> 5) & 31, oxx = o & 31;
  float s = ob[0];
#pragma unroll
  for (int c = 0; c < 32; ++c)
    s += ow[c] * (float)hp[((size_t)(b * 32 + c) * 32 + oy) * 96 + oxx + 31];
  out[o] = s;
}

extern "C" void kernel_launch(void* const* d_in, const int* in_sizes, int n_in,
                              void* d_out, int out_size, void* d_ws,
                              size_t ws_size, hipStream_t stream) {
  const float* x = (const float*)d_in[0];
  const float* in_w = (const float*)d_in[1];
  const float* in_b = (const float*)d_in[2];
  const float* convs_w = (const float*)d_in[3];
  const float* convs_b = (const float*)d_in[4];
  const float* out_w = (const float*)d_in[5];
  const float* out_b = (const float*)d_in[6];
  float* out = (float*)d_out;

  char* ws = (char*)d_ws;
  f16* xpad = (f16*)ws;                               //    98,304 B
  f16* hpA = (f16*)(ws + 98304);                      // 3,145,728 B
  f16* hpB = (f16*)(ws + 98304 + 3145728);            // 3,145,728 B
  f16* WfIn = (f16*)(ws + 6389760);                   //    65,536 B
  f16* WfH = (f16*)(ws + 6455296);                    // 41,943,040 B
  const bool pre = (ws_size >= 48398336ull);

  pad_x_kernel<<<188, 256, 0, stream>>>(x, xpad);
  if (pre) convert_w3<<<2048, 256, 0, stream>>>(in_w, convs_w, WfIn, WfH);

  if (pre)
    gemm3<1, false, true><<<512, 512, 0, stream>>>(WfIn, xpad, in_b, hpA);
  else
    gemm3<1, false, false><<<512, 512, 0, stream>>>(in_w, xpad, in_b, hpA);

  for (int l = 0; l < 20; ++l) {
    const f16* cur = (l % 2 == 0) ? hpA : hpB;
    f16* nxt = (l % 2 == 0) ? hpB : hpA;
    if (pre)
      gemm3<32, true, true><<<512, 512, 0, stream>>>(
          WfH + (size_t)l * 1048576, cur, convs_b + 32 * l, nxt);
    else
      gemm3<32, true, false><<<512, 512, 0, stream>>>(
          convs_w + (size_t)l * 1048576, cur, convs_b + 32 * l, nxt);
  }

  // after l=19 (odd): output in hpA
  out_conv3<<<64, 256, 0, stream>>>(hpA, out_w, out_b, out);
}

// Round 7
// 1157.988 us; speedup vs baseline: 1.0143x; 1.0143x over previous
//
#include <hip/hip_runtime.h>

// GoL CNN v8: barrier-free K-loop. Evidence from v4-v7: every pipe <35% busy
// at any occupancy; VGPR collapses (96/36) because the per-epoch barrier +
// sched_barrier fences forbid cross-channel pipelining -> latency-bound.
// Fix: B fragments are tiny (6 rows x 192 B/channel) and L2-resident, so
// load them DIRECTLY from global hpad. No rowbuf, no staging, no K-loop
// barriers or fences at all. Explicit distance-1 double-buffered pipeline
// (A0/F0 vs A1/F1) under a 256-VGPR budget (launch_bounds(512,2)).
// Math identical to v5 (consecutive-ky, 2 rows/block, 8-way K-split).

typedef _Float16 f16;
typedef _Float16 f16x8 __attribute__((ext_vector_type(8)));
typedef float f32x4 __attribute__((ext_vector_type(4)));
typedef float f32x16 __attribute__((ext_vector_type(16)));
typedef int i4a __attribute__((ext_vector_type(4), aligned(4)));  // 16B ld, 4B align

// iterated wrap-pad index map, j in [0,94): middle j-31; borders alternate.
__device__ __forceinline__ int mwrap(int j) {
  int t = j - 31;
  if ((unsigned)t <= 31u) return t;          // middle
  if (t < 0) return (j & 1) ? 0 : 31;        // left border
  return (j & 1) ? 0 : 31;                   // right border
}

// hpad layout: [16b][32ch][32y][96x] f16 (x' in [0,94) valid)
// Wf frag-major: per layer, chunk=(c*32+ky)*2+kxh, then [lane(64)][8 f16]
//   lane: co=lane&31, s=lane>>5; elements w[co][c][ky][kxh*16+s*8+j]

// 16 MFMAs consuming register-resident fragments (no memory access).
#define MFMAC(AUSE, FD)                                                      \
  {                                                                          \
    _Pragma("unroll")                                                        \
    for (int kyi_ = 0; kyi_ < 4; ++kyi_) {                                   \
      _Pragma("unroll")                                                      \
      for (int kxh_ = 0; kxh_ < 2; ++kxh_) {                                 \
        const f16x8 a_ = AUSE[kyi_ * 2 + kxh_];                              \
        acc0 = __builtin_amdgcn_mfma_f32_32x32x16_f16(a_, FD[kyi_][kxh_],    \
                                                      acc0, 0, 0, 0);        \
        acc1 = __builtin_amdgcn_mfma_f32_32x32x16_f16(a_, FD[kyi_ + 2][kxh_],\
                                                      acc1, 0, 0, 0);        \
      }                                                                      \
    }                                                                        \
  }

template <int CIN, bool RELU, bool PRE>
__global__ __launch_bounds__(512, 2) void gemm3(
    const void* __restrict__ Wv,       // PRE: f16 frag-major; else fp32 raw
    const f16* __restrict__ hp_in,     // [16][CIN][32][96]
    const float* __restrict__ bias,    // [32]
    f16* __restrict__ hp_out) {        // [16][32][32][96]
  __shared__ float Red[8][2][1024];    // 64 KB (reduction only)

  const int tid = threadIdx.x;
  const int lane = tid & 63;
  const int w = tid >> 6;        // wave 0..7: owns ky in {4w..4w+3}
  const int ox = lane & 31;      // B n-index / A m-index (co)
  const int s = lane >> 5;       // k-half within mfma

  const int pair0 = blockIdx.x * 2;
  const int b = pair0 >> 5;
  const int oy0 = pair0 & 31;    // pair0 even -> oy0, oy0+1 same batch

  // B-fragment row dword-pointers (global), loop-invariant except +48/ch:
  // acc0 (row oy0):   y = mwrap(2*oy0 + 4w + j), j=0..3
  // acc1 (row oy0+1): same rows shifted by 2 -> j=2..5
  const int bi = ox + 4 * s;
  const int* Rb[6];
#pragma unroll
  for (int j = 0; j < 6; ++j)
    Rb[j] = (const int*)hp_in +
            ((size_t)b * CIN * 32 + mwrap(2 * oy0 + 4 * w + j)) * 48 + bi;

  f32x16 acc0 = {}, acc1 = {};   // per pair
  f16x8 A0[8], A1[8];
  f16x8 F0[6][2], F1[6][2];

  auto loadA = [&](int c, f16x8* dst) {
#pragma unroll
    for (int kyi = 0; kyi < 4; ++kyi) {
#pragma unroll
      for (int kxh = 0; kxh < 2; ++kxh) {
        const int ky = 4 * w + kyi;
        const int chunk = (c * 32 + ky) * 2 + kxh;
        if constexpr (PRE) {
          const f16* Wl = (const f16*)Wv;
          dst[kyi * 2 + kxh] = *(const f16x8*)(Wl + (size_t)chunk * 512 + lane * 8);
        } else {
          const float* Wl = (const float*)Wv;
          const float* sp = Wl + (((size_t)(ox * CIN + c) * 32 + ky) * 32 + kxh * 16 + s * 8);
          f32x4 u0 = *(const f32x4*)sp;
          f32x4 u1 = *(const f32x4*)(sp + 4);
          f16x8 v;
          v[0] = (f16)u0[0]; v[1] = (f16)u0[1]; v[2] = (f16)u0[2]; v[3] = (f16)u0[3];
          v[4] = (f16)u1[0]; v[5] = (f16)u1[1]; v[6] = (f16)u1[2]; v[7] = (f16)u1[3];
          dst[kyi * 2 + kxh] = v;
        }
      }
    }
  };
  // 12 B-fragments of channel c, straight from global (L1/L2-resident).
  auto loadF = [&](int c, f16x8 (*FD)[2]) {
    const int coff = c * 48 * 32;  // dwords per channel plane
#pragma unroll
    for (int j = 0; j < 6; ++j) {
      const int* R = Rb[j] + coff;
      FD[j][0] = __builtin_bit_cast(f16x8, *(const i4a*)(R));
      FD[j][1] = __builtin_bit_cast(f16x8, *(const i4a*)(R + 8));
    }
  };

  if constexpr (CIN == 1) {
    loadA(0, A0);
    loadF(0, F0);
    MFMAC(A0, F0);
  } else {
    static_assert(CIN % 2 == 0, "CIN must be 1 or even");
    loadA(0, A0);
    loadF(0, F0);
#pragma unroll 1
    for (int c = 0; c < CIN; c += 2) {
      loadA(c + 1, A1);          // next-channel loads in flight during MFMAs
      loadF(c + 1, F1);
      MFMAC(A0, F0);             // c
      if (c + 2 < CIN) {
        loadA(c + 2, A0);
        loadF(c + 2, F0);
      }
      MFMAC(A1, F1);             // c+1
    }
  }

  // one-shot 8-way K reduction: every wave dumps, all 512 threads re-reduce
  __syncthreads();               // (only sync in the kernel)
#pragma unroll
  for (int r = 0; r < 16; ++r) {
    Red[w][0][r * 64 + lane] = acc0[r];
    Red[w][1][r * 64 + lane] = acc1[r];
  }
  __syncthreads();

#pragma unroll
  for (int k4 = 0; k4 < 4; ++k4) {
    const int o = tid + 512 * k4;          // 2048 outputs: [p][co][ox]
    const int p = o >> 10, co = (o >> 5) & 31, oxx = o & 31;
    const int idx = ((co & 3) + 4 * (co >> 3)) * 64 + ((co >> 2) & 1) * 32 + oxx;
    float v = bias[co];
#pragma unroll
    for (int w8 = 0; w8 < 8; ++w8) v += Red[w8][p][idx];
    if (RELU) v = fmaxf(v, 0.f);
    const f16 hv = (f16)v;
    f16* base = hp_out + ((size_t)(b * 32 + co) * 32 + (oy0 + p)) * 96;
    base[oxx + 31] = hv;
    if (oxx == 0) {
#pragma unroll
      for (int j = 1; j <= 29; j += 2) base[j] = hv;
#pragma unroll
      for (int j = 63; j <= 93; j += 2) base[j] = hv;
    }
    if (oxx == 31) {
#pragma unroll
      for (int j = 0; j <= 30; j += 2) base[j] = hv;
#pragma unroll
      for (int j = 64; j <= 92; j += 2) base[j] = hv;
    }
  }
}

// x (fp32 [16][1][32][32]) -> xpad f16 [16][1][32][96]
__global__ void pad_x_kernel(const float* __restrict__ x, f16* __restrict__ xp) {
  const int i = blockIdx.x * 256 + threadIdx.x;  // 16*32*94 = 48128
  if (i >= 48128) return;
  const int bq = i / 3008, r = i - bq * 3008;
  const int y = r / 94, j = r - y * 94;
  xp[bq * 3072 + y * 96 + j] = (f16)x[(bq * 32 + y) * 32 + mwrap(j)];
}

// build frag-major f16 weights: in_w (64 chunks) + 20 hidden layers (2048 each)
__global__ void convert_w3(const float* __restrict__ in_w,
                           const float* __restrict__ convs_w,
                           f16* __restrict__ WfIn, f16* __restrict__ WfH) {
  const int total = 4096 + 20 * 131072;  // units of (chunk,lane)
  for (int g = blockIdx.x * blockDim.x + threadIdx.x; g < total;
       g += gridDim.x * blockDim.x) {
    const float* src;
    f16* dst;
    int chunk, lanE, c, ky, kxh;
    if (g < 4096) {
      chunk = g >> 6; lanE = g & 63;
      kxh = chunk & 1; ky = chunk >> 1; c = 0;
      const int co = lanE & 31, ss = lanE >> 5;
      src = in_w + ((size_t)(co * 1 + 0) * 32 + ky) * 32 + kxh * 16 + ss * 8;
      dst = WfIn + (size_t)chunk * 512 + lanE * 8;
    } else {
      const int h = g - 4096;
      const int layer = h >> 17, r = h & 131071;
      chunk = r >> 6; lanE = r & 63;
      kxh = chunk & 1;
      const int t = chunk >> 1;
      ky = t & 31; c = t >> 5;
      const int co = lanE & 31, ss = lanE >> 5;
      src = convs_w + (size_t)layer * 1048576 +
            ((size_t)(co * 32 + c) * 32 + ky) * 32 + kxh * 16 + ss * 8;
      dst = WfH + (size_t)layer * 1048576 + (size_t)chunk * 512 + lanE * 8;
    }
    f32x4 u0 = *(const f32x4*)src;
    f32x4 u1 = *(const f32x4*)(src + 4);
    f16x8 v;
    v[0] = (f16)u0[0]; v[1] = (f16)u0[1]; v[2] = (f16)u0[2]; v[3] = (f16)u0[3];
    v[4] = (f16)u1[0]; v[5] = (f16)u1[1]; v[6] = (f16)u1[2]; v[7] = (f16)u1[3];
    *(f16x8*)dst = v;
  }
}

// 1x1 out conv from hpad final: out[b][0][oy][ox] fp32
__global__ void out_conv3(const f16* __restrict__ hp,
                          const float* __restrict__ ow,
                          const float* __restrict__ ob,
                          float* __restrict__ out) {
  const int o = blockIdx.x * 256 + threadIdx.x;  // 16384
  const int b = o >> 10, oy = (o >> 5) & 31, oxx = o & 31;
  float s = ob[0];
#pragma unroll
  for (int c = 0; c < 32; ++c)
    s += ow[c] * (float)hp[((size_t)(b * 32 + c) * 32 + oy) * 96 + oxx + 31];
  out[o] = s;
}

extern "C" void kernel_launch(void* const* d_in, const int* in_sizes, int n_in,
                              void* d_out, int out_size, void* d_ws,
                              size_t ws_size, hipStream_t stream) {
  const float* x = (const float*)d_in[0];
  const float* in_w = (const float*)d_in[1];
  const float* in_b = (const float*)d_in[2];
  const float* convs_w = (const float*)d_in[3];
  const float* convs_b = (const float*)d_in[4];
  const float* out_w = (const float*)d_in[5];
  const float* out_b = (const float*)d_in[6];
  float* out = (float*)d_out;

  char* ws = (char*)d_ws;
  f16* xpad = (f16*)ws;                               //    98,304 B
  f16* hpA = (f16*)(ws + 98304);                      // 3,145,728 B
  f16* hpB = (f16*)(ws + 98304 + 3145728);            // 3,145,728 B
  f16* WfIn = (f16*)(ws + 6389760);                   //    65,536 B
  f16* WfH = (f16*)(ws + 6455296);                    // 41,943,040 B
  const bool pre = (ws_size >= 48398336ull);

  pad_x_kernel<<<188, 256, 0, stream>>>(x, xpad);
  if (pre) convert_w3<<<2048, 256, 0, stream>>>(in_w, convs_w, WfIn, WfH);

  if (pre)
    gemm3<1, false, true><<<256, 512, 0, stream>>>(WfIn, xpad, in_b, hpA);
  else
    gemm3<1, false, false><<<256, 512, 0, stream>>>(in_w, xpad, in_b, hpA);

  for (int l = 0; l < 20; ++l) {
    const f16* cur = (l % 2 == 0) ? hpA : hpB;
    f16* nxt = (l % 2 == 0) ? hpB : hpA;
    if (pre)
      gemm3<32, true, true><<<256, 512, 0, stream>>>(
          WfH + (size_t)l * 1048576, cur, convs_b + 32 * l, nxt);
    else
      gemm3<32, true, false><<<256, 512, 0, stream>>>(
          convs_w + (size_t)l * 1048576, cur, convs_b + 32 * l, nxt);
  }

  // after l=19 (odd): output in hpA
  out_conv3<<<64, 256, 0, stream>>>(hpA, out_w, out_b, out);
}